// Round 14
// baseline (88.880 us; speedup 1.0000x reference)
//
#include <hip/hip_runtime.h>
#include <hip/hip_bf16.h>

typedef __attribute__((ext_vector_type(8))) short short8;
typedef __attribute__((ext_vector_type(4))) float floatx4;

#define L2EPS 1e-12f

__device__ __forceinline__ unsigned short f2bf(float f) {
  union { float f; unsigned u; } c; c.f = f;
  unsigned u = c.u;
  unsigned r = (u + 0x7fffu + ((u >> 16) & 1u)) >> 16;  // RNE
  return (unsigned short)r;
}

__device__ __forceinline__ void gload_lds16(const void* g, void* l) {
  __builtin_amdgcn_global_load_lds(
      (const __attribute__((address_space(1))) unsigned int*)g,
      (__attribute__((address_space(3))) unsigned int*)l,
      16, 0, 0);
}

// ---------------------------------------------------------------------------
// Kernel 1: per-row inverse L2 norm of W. One block/row.
// ---------------------------------------------------------------------------
__global__ __launch_bounds__(256) void wnorm_kernel(const float* __restrict__ W,
                                                    float* __restrict__ rnw, int N) {
  const int d = blockIdx.x;
  const float2* row2 = (const float2*)(W + (size_t)d * N);
  const int n2 = N >> 1;
  float s = 0.f;
  for (int i = threadIdx.x; i < n2; i += 256) {
    const float2 v = row2[i];
    s += v.x * v.x + v.y * v.y;
  }
  if (threadIdx.x == 0 && (N & 1)) {
    const float v = W[(size_t)d * N + (N - 1)];
    s += v * v;
  }
#pragma unroll
  for (int off = 32; off > 0; off >>= 1) s += __shfl_xor(s, off);
  __shared__ float red[4];
  if ((threadIdx.x & 63) == 0) red[threadIdx.x >> 6] = s;
  __syncthreads();
  if (threadIdx.x == 0)
    rnw[d] = rsqrtf(fmaxf(red[0] + red[1] + red[2] + red[3], L2EPS));
}

// ---------------------------------------------------------------------------
// Kernel 2 (fused dispatch): blocks [0,nxb): normalize x rows AND fold rnw.
// Blocks [nxb,...): transpose-cast BT[n][d] = bf16(W[d][n]), zero-padded.
// ---------------------------------------------------------------------------
__global__ __launch_bounds__(256) void prep_kernel(const float* __restrict__ x,
                                                   const float* __restrict__ W,
                                                   const float* __restrict__ rnw,
                                                   unsigned short* __restrict__ xb,
                                                   unsigned short* __restrict__ BT,
                                                   int N, int nxb, int nwx) {
  const int bid = blockIdx.x;
  if (bid < nxb) {
    const int lane = threadIdx.x & 63;
    const int wave = threadIdx.x >> 6;
    const int row  = bid * 4 + wave;
    const float4* xr = (const float4*)(x + (size_t)row * 512);
    const float4 v0 = xr[lane * 2];
    const float4 v1 = xr[lane * 2 + 1];
    float s = v0.x*v0.x + v0.y*v0.y + v0.z*v0.z + v0.w*v0.w
            + v1.x*v1.x + v1.y*v1.y + v1.z*v1.z + v1.w*v1.w;
#pragma unroll
    for (int off = 32; off > 0; off >>= 1) s += __shfl_xor(s, off);
    const float r = rsqrtf(fmaxf(s, L2EPS));
    const float4 w0 = ((const float4*)rnw)[lane * 2];
    const float4 w1 = ((const float4*)rnw)[lane * 2 + 1];
    short8 o;
    o[0] = (short)f2bf(v0.x * r * w0.x); o[1] = (short)f2bf(v0.y * r * w0.y);
    o[2] = (short)f2bf(v0.z * r * w0.z); o[3] = (short)f2bf(v0.w * r * w0.w);
    o[4] = (short)f2bf(v1.x * r * w1.x); o[5] = (short)f2bf(v1.y * r * w1.y);
    o[6] = (short)f2bf(v1.z * r * w1.z); o[7] = (short)f2bf(v1.w * r * w1.w);
    *(short8*)(xb + (size_t)row * 512 + lane * 8) = o;
  } else {
    __shared__ unsigned short tile[32][33];
    const int wb = bid - nxb;
    const int n0 = (wb % nwx) * 32;
    const int d0 = (wb / nwx) * 32;
    const int tx = threadIdx.x & 31;
    const int ty = threadIdx.x >> 5;  // 0..7
#pragma unroll
    for (int i = 0; i < 4; ++i) {
      const int dl = ty + i * 8;
      const int n = n0 + tx;
      float v = 0.f;
      if (n < N) v = W[(size_t)(d0 + dl) * N + n];
      tile[tx][dl] = f2bf(v);
    }
    __syncthreads();
#pragma unroll
    for (int i = 0; i < 4; ++i) {
      const int nl = ty + i * 8;
      BT[(size_t)(n0 + nl) * 512 + d0 + tx] = tile[nl][tx];
    }
  }
}

// ---------------------------------------------------------------------------
// Kernel 3: WHOLE-K single-burst GEMM. Tile 64x96, K=512 staged entirely in
// one 20-instr DMA burst (A 64KB + B 96KB = 160KB LDS, 1 block/CU, 512 thr,
// 8 waves as 4M x 2N of 16x48). ONE vmcnt(0) + ONE barrier per block, then
// pure LDS+MFMA (fully static). Latency paid once per block, not per K-tile.
// Rows are 1024B: 8-chunk XOR swizzle within each aligned 128B group
// (phys_k = (k&56)|((k&7)^(row&7))) -> every 8-lane group spans all 32
// banks (0 conflicts, same family measured 0 in r3). Source pre-swizzled
// (rule #21). XCD rects 16by x 32bx, by-fast -> B-tile reused 16x from L2.
// ---------------------------------------------------------------------------
__global__ __launch_bounds__(512, 1) void gemm_kernel(
    const unsigned short* __restrict__ A,   // (4096,512) bf16 (xn * rnw)
    const unsigned short* __restrict__ BT,  // (6144,512) bf16 (W^T, padded)
    float* __restrict__ C,                  // (4096,N) f32
    int N) {
  __shared__ unsigned short As[64 * 512];   // 64 KB
  __shared__ unsigned short Bs[96 * 512];   // 96 KB

  const int tid  = threadIdx.x;
  const int lane = tid & 63;
  const int w    = tid >> 6;   // 0..7

  // XCD rects: 4096 blocks = 8 rects x 512; rect c = (c&3) by-band x (c>>2)
  // bx-band; by fast within rect (16 consecutive blocks share the B-tile).
  const int bid = blockIdx.x;
  const int c   = bid & 7;
  const int i   = bid >> 3;                   // 0..511
  const int by  = (c & 3) * 16 + (i & 15);    // 0..63
  const int bx  = (c >> 2) * 32 + (i >> 4);   // 0..63
  const int row0 = by * 64;
  const int col0 = bx * 96;

  // ---- single staging burst: 20 x (512 thr x 16B) = 160KB ----
  // dest linear: row*1024B + lane*16B per wave-instr (wave-uniform + lane*16).
  // source k-chunk pre-swizzled: g = (lane&56) | ((lane&7) ^ w); row%8 == w.
  const int sch = ((lane & 56) | ((lane & 7) ^ w)) * 8;    // elems
  const unsigned short* Asrc = A  + (size_t)(row0 + w) * 512 + sch;
  const unsigned short* Bsrc = BT + (size_t)(col0 + w) * 512 + sch;
  const int ldst = w * 512 + lane * 8;                     // elems
#pragma unroll
  for (int ii = 0; ii < 8; ++ii)
    gload_lds16(Asrc + (size_t)ii * 4096, &As[ldst + ii * 4096]);
#pragma unroll
  for (int ii = 0; ii < 12; ++ii)
    gload_lds16(Bsrc + (size_t)ii * 4096, &Bs[ldst + ii * 4096]);
  asm volatile("s_waitcnt vmcnt(0)" ::: "memory");
  __syncthreads();

  // ---- compute: wave (wr2=w&3, wc2=w>>2) owns rows wr2*16+[0,16),
  //      cols wc2*48+[0,48). 16 k-steps x (1 af + 3 bf reads + 3 MFMA). ----
  const int ln15 = lane & 15;
  const int q4   = lane >> 4;
  const int e7   = ln15 & 7;
  const int wr2  = w & 3;
  const int wc2  = w >> 2;
  const int arow = (wr2 * 16 + ln15) * 512;
  const int brow0 = (wc2 * 48 + ln15) * 512;     // + j*16*512

  floatx4 acc[3];
#pragma unroll
  for (int j = 0; j < 3; ++j) acc[j] = (floatx4){0.f, 0.f, 0.f, 0.f};

#pragma unroll
  for (int ks = 0; ks < 16; ++ks) {
    const int k  = ks * 4 + q4;
    const int pk = ((k & 56) | ((k & 7) ^ e7)) * 8;    // swizzled chunk (elems)
    const short8 af = *(const short8*)&As[arow + pk];
#pragma unroll
    for (int j = 0; j < 3; ++j) {
      const short8 bf = *(const short8*)&Bs[brow0 + j * 8192 + pk];
      acc[j] = __builtin_amdgcn_mfma_f32_16x16x32_bf16(af, bf, acc[j], 0, 0, 0);
    }
  }

  // ---- epilogue: C/D layout col=lane&15, row=(lane>>4)*4+r ----
  const int rb = row0 + wr2 * 16 + q4 * 4;
  const int cb = col0 + wc2 * 48 + ln15;
#pragma unroll
  for (int j = 0; j < 3; ++j) {
    const int col = cb + j * 16;
    if (col < N) {
#pragma unroll
      for (int r = 0; r < 4; ++r)
        C[(size_t)(rb + r) * N + col] = acc[j][r];
    }
  }
}

// ---------------------------------------------------------------------------
extern "C" void kernel_launch(void* const* d_in, const int* in_sizes, int n_in,
                              void* d_out, int out_size, void* d_ws, size_t ws_size,
                              hipStream_t stream) {
  const float* x = (const float*)d_in[0];
  const float* W = (const float*)d_in[1];
  float* out = (float*)d_out;

  const int D = 512;
  const int B = in_sizes[0] / D;            // 4096
  const int N = in_sizes[1] / D;            // 5994
  const int Npad = 6144;                    // 64 x 96

  char* ws = (char*)d_ws;
  unsigned short* xb  = (unsigned short*)ws;                          // B*D*2
  unsigned short* BTb = (unsigned short*)(ws + (size_t)B * D * 2);    // Npad*D*2
  float* rnw = (float*)(ws + (size_t)B * D * 2 + (size_t)Npad * D * 2);

  const int nxb = B / 4;           // 1024 xnorm blocks
  const int nwx = Npad / 32;       // 192 wtrans tiles per d-stripe
  const int nwb = nwx * (D / 32);  // 3072 wtrans blocks

  wnorm_kernel<<<D, 256, 0, stream>>>(W, rnw, N);
  prep_kernel<<<nxb + nwb, 256, 0, stream>>>(x, W, rnw, xb, BTb, N, nxb, nwx);
  gemm_kernel<<<(B / 64) * (Npad / 96), 512, 0, stream>>>(xb, BTb, out, N);
}

// Round 15
// 60.728 us; speedup vs baseline: 1.4636x; 1.4636x over previous
//
#include <hip/hip_runtime.h>
#include <hip/hip_bf16.h>

typedef __attribute__((ext_vector_type(8))) short short8;
typedef __attribute__((ext_vector_type(4))) float floatx4;
typedef __attribute__((ext_vector_type(2))) float floatx2;

#define L2EPS 1e-12f

__device__ __forceinline__ unsigned short f2bf(float f) {
  union { float f; unsigned u; } c; c.f = f;
  unsigned u = c.u;
  unsigned r = (u + 0x7fffu + ((u >> 16) & 1u)) >> 16;  // RNE
  return (unsigned short)r;
}

__device__ __forceinline__ void gload_lds16(const void* g, void* l) {
  __builtin_amdgcn_global_load_lds(
      (const __attribute__((address_space(1))) unsigned int*)g,
      (__attribute__((address_space(3))) unsigned int*)l,
      16, 0, 0);
}

// ---------------------------------------------------------------------------
// Kernel 1: per-row inverse L2 norm of W (D rows of length N). One block/row.
// ---------------------------------------------------------------------------
__global__ __launch_bounds__(256) void wnorm_kernel(const float* __restrict__ W,
                                                    float* __restrict__ rnw, int N) {
  const int d = blockIdx.x;
  const float2* row2 = (const float2*)(W + (size_t)d * N);
  const int n2 = N >> 1;
  float s = 0.f;
  for (int i = threadIdx.x; i < n2; i += 256) {
    const float2 v = row2[i];
    s += v.x * v.x + v.y * v.y;
  }
  if (threadIdx.x == 0 && (N & 1)) {
    const float v = W[(size_t)d * N + (N - 1)];
    s += v * v;
  }
#pragma unroll
  for (int off = 32; off > 0; off >>= 1) s += __shfl_xor(s, off);
  __shared__ float red[4];
  if ((threadIdx.x & 63) == 0) red[threadIdx.x >> 6] = s;
  __syncthreads();
  if (threadIdx.x == 0)
    rnw[d] = rsqrtf(fmaxf(red[0] + red[1] + red[2] + red[3], L2EPS));
}

// ---------------------------------------------------------------------------
// Kernel 2 (fused dispatch): blocks [0,nxb): normalize x rows AND fold rnw.
// Blocks [nxb,...): transpose-cast BT[n][d] = bf16(W[d][n]), zero-padded.
// ---------------------------------------------------------------------------
__global__ __launch_bounds__(256) void prep_kernel(const float* __restrict__ x,
                                                   const float* __restrict__ W,
                                                   const float* __restrict__ rnw,
                                                   unsigned short* __restrict__ xb,
                                                   unsigned short* __restrict__ BT,
                                                   int N, int nxb, int nwx) {
  const int bid = blockIdx.x;
  if (bid < nxb) {
    const int lane = threadIdx.x & 63;
    const int wave = threadIdx.x >> 6;
    const int row  = bid * 4 + wave;
    const float4* xr = (const float4*)(x + (size_t)row * 512);
    const float4 v0 = xr[lane * 2];
    const float4 v1 = xr[lane * 2 + 1];
    float s = v0.x*v0.x + v0.y*v0.y + v0.z*v0.z + v0.w*v0.w
            + v1.x*v1.x + v1.y*v1.y + v1.z*v1.z + v1.w*v1.w;
#pragma unroll
    for (int off = 32; off > 0; off >>= 1) s += __shfl_xor(s, off);
    const float r = rsqrtf(fmaxf(s, L2EPS));
    const float4 w0 = ((const float4*)rnw)[lane * 2];
    const float4 w1 = ((const float4*)rnw)[lane * 2 + 1];
    short8 o;
    o[0] = (short)f2bf(v0.x * r * w0.x); o[1] = (short)f2bf(v0.y * r * w0.y);
    o[2] = (short)f2bf(v0.z * r * w0.z); o[3] = (short)f2bf(v0.w * r * w0.w);
    o[4] = (short)f2bf(v1.x * r * w1.x); o[5] = (short)f2bf(v1.y * r * w1.y);
    o[6] = (short)f2bf(v1.z * r * w1.z); o[7] = (short)f2bf(v1.w * r * w1.w);
    *(short8*)(xb + (size_t)row * 512 + lane * 8) = o;
  } else {
    __shared__ unsigned short tile[32][33];
    const int wb = bid - nxb;
    const int n0 = (wb % nwx) * 32;
    const int d0 = (wb / nwx) * 32;
    const int tx = threadIdx.x & 31;
    const int ty = threadIdx.x >> 5;  // 0..7
#pragma unroll
    for (int i = 0; i < 4; ++i) {
      const int dl = ty + i * 8;
      const int n = n0 + tx;
      float v = 0.f;
      if (n < N) v = W[(size_t)(d0 + dl) * N + n];
      tile[tx][dl] = f2bf(v);
    }
    __syncthreads();
#pragma unroll
    for (int i = 0; i < 4; ++i) {
      const int nl = ty + i * 8;
      BT[(size_t)(n0 + nl) * 512 + d0 + tx] = tile[nl][tx];
    }
  }
}

// ---------------------------------------------------------------------------
// Kernel 3: GEMM = r8 skeleton EXACTLY (128x128, 4 waves, BK=64, single LDS
// buffer, compiler-owned schedule, chunk-XOR swizzle both sides, XCD column
// chunks, 4 blocks/CU) + ONE change: paired-float2 epilogue. One
// __shfl_xor(.,1) per fragment pairs adjacent columns across even/odd lanes
// -> 32 8B-aligned dwordx2 stores/thread instead of 64 scalars (row stride
// 5994*4 = 23976 B ≡ 0 mod 8 and cols even => alignment guaranteed; same
// 64B-contiguous segments per 8-lane group => same measured-near-ideal
// WRITE ~103MB, half the store-issue and drain cost).
// ---------------------------------------------------------------------------
__global__ __launch_bounds__(256, 4) void gemm_kernel(
    const unsigned short* __restrict__ A,   // (4096,512) bf16 (xn * rnw)
    const unsigned short* __restrict__ BT,  // (6016,512) bf16 (W^T)
    float* __restrict__ C,                  // (4096,N) f32
    int N, int nbx, int nby) {
  __shared__ unsigned short As[128 * 64];
  __shared__ unsigned short Bs[128 * 64];

  const int tid = threadIdx.x;
  const int l   = tid & 63;
  const int w   = tid >> 6;   // 0..3
  const int wr  = w >> 1;     // 0..1
  const int wc  = w & 1;      // 0..1

  // XCD swizzle: 1504 = 8 x 188; column-major chunks (B-panel L2 reuse).
  const int grid = nbx * nby;
  const int bid  = blockIdx.x;
  int swz = bid;
  if ((grid & 7) == 0) swz = (bid & 7) * (grid >> 3) + (bid >> 3);
  const int bx = swz / nby;
  const int by = swz % nby;
  const int row0 = by * 128;
  const int col0 = bx * 128;

  floatx4 acc[4][4];
#pragma unroll
  for (int m = 0; m < 4; ++m)
#pragma unroll
    for (int n = 0; n < 4; ++n)
      acc[m][n] = (floatx4){0.f, 0.f, 0.f, 0.f};

  // staging: one instr = 256 thr x 16B = 4KB = 32 rows of 128B; 4 per matrix.
  // LDS dest linear (tid*16B); SOURCE chunk pre-swizzled (rule #21):
  // chunk_g = (tid&7) ^ (row&7), row&7 = (tid>>3)&7 (rows step by 32).
  const int srow = tid >> 3;                               // 0..31
  const int sch  = ((tid & 7) ^ (srow & 7)) * 8;           // elems
  const unsigned short* Ap = A  + (size_t)(row0 + srow) * 512 + sch;
  const unsigned short* Bp = BT + (size_t)(col0 + srow) * 512 + sch;
  const int lo = tid * 8;                                  // LDS elems

  // frag-read geometry: elem = row*64 + ((ks*4+q4)^(row&7))*8; consecutive
  // 8-lane groups cover 8 distinct 16B bank-groups (0 conflicts, r3-measured).
  const int ln15 = l & 15;
  const int q4   = l >> 4;
  const int e7   = ln15 & 7;
  const int cs0  = ((q4) ^ e7) * 8;
  const int cs1  = ((4 + q4) ^ e7) * 8;
  const int aoff = (wr * 64 + ln15) * 64;   // + m*1024
  const int boff = (wc * 64 + ln15) * 64;   // + n*1024

  for (int t = 0; t < 8; ++t) {
#pragma unroll
    for (int i = 0; i < 4; ++i)
      gload_lds16(Ap + (size_t)(i * 32) * 512 + t * 64, &As[i * 2048 + lo]);
#pragma unroll
    for (int i = 0; i < 4; ++i)
      gload_lds16(Bp + (size_t)(i * 32) * 512 + t * 64, &Bs[i * 2048 + lo]);
    __syncthreads();
#pragma unroll
    for (int ks = 0; ks < 2; ++ks) {
      const int cs = ks ? cs1 : cs0;
      short8 af[4], bf[4];
#pragma unroll
      for (int m = 0; m < 4; ++m) af[m] = *(const short8*)&As[aoff + m * 1024 + cs];
#pragma unroll
      for (int n = 0; n < 4; ++n) bf[n] = *(const short8*)&Bs[boff + n * 1024 + cs];
#pragma unroll
      for (int m = 0; m < 4; ++m)
#pragma unroll
        for (int n = 0; n < 4; ++n)
          acc[m][n] = __builtin_amdgcn_mfma_f32_16x16x32_bf16(af[m], bf[n], acc[m][n], 0, 0, 0);
    }
    __syncthreads();
  }

  // ---- paired-float2 epilogue ----
  // Original mapping: C[rb + m*16 + r][cb + n*16] = acc[m][n][r],
  //   rb = row0 + wr*64 + q4*4, cb = col0 + wc*64 + ln15.
  // Pair even/odd ln15 lanes via shfl_xor(1): even lane stores rows {0,1},
  // odd lane rows {2,3}, each as one float2 covering cols {2a, 2a+1}.
  const int odd  = ln15 & 1;
  const int rb   = row0 + wr * 64 + q4 * 4 + (odd ? 2 : 0);
  const int cb2  = col0 + wc * 64 + (ln15 & ~1);
#pragma unroll
  for (int m = 0; m < 4; ++m) {
#pragma unroll
    for (int n = 0; n < 4; ++n) {
      const floatx4 a = acc[m][n];
      const float slo = odd ? a[0] : a[2];
      const float shi = odd ? a[1] : a[3];
      const float rlo = __shfl_xor(slo, 1);
      const float rhi = __shfl_xor(shi, 1);
      floatx2 v0, v1;
      v0[0] = odd ? rlo : a[0];  v0[1] = odd ? a[2] : rlo;
      v1[0] = odd ? rhi : a[1];  v1[1] = odd ? a[3] : rhi;
      const int c2 = cb2 + n * 16;
      if (c2 < N) {  // c2 even, N even -> full pair in bounds when c2 < N
        const size_t o0 = (size_t)(rb + m * 16) * N + c2;
        *(floatx2*)&C[o0]     = v0;
        *(floatx2*)&C[o0 + N] = v1;
      }
    }
  }
}

// ---------------------------------------------------------------------------
extern "C" void kernel_launch(void* const* d_in, const int* in_sizes, int n_in,
                              void* d_out, int out_size, void* d_ws, size_t ws_size,
                              hipStream_t stream) {
  const float* x = (const float*)d_in[0];
  const float* W = (const float*)d_in[1];
  float* out = (float*)d_out;

  const int D = 512;
  const int B = in_sizes[0] / D;            // 4096
  const int N = in_sizes[1] / D;            // 5994
  const int Npad = ((N + 127) / 128) * 128; // 6016

  char* ws = (char*)d_ws;
  unsigned short* xb  = (unsigned short*)ws;                          // B*D*2
  unsigned short* BTb = (unsigned short*)(ws + (size_t)B * D * 2);    // Npad*D*2
  float* rnw = (float*)(ws + (size_t)B * D * 2 + (size_t)Npad * D * 2);

  const int nby = B / 128;         // 32
  const int nbx = Npad / 128;      // 47
  const int nxb = B / 4;           // 1024 xnorm blocks
  const int nwx = Npad / 32;       // 188 wtrans tiles per d-stripe
  const int nwb = nwx * (D / 32);  // 3008 wtrans blocks

  wnorm_kernel<<<D, 256, 0, stream>>>(W, rnw, N);
  prep_kernel<<<nxb + nwb, 256, 0, stream>>>(x, W, rnw, xb, BTb, N, nxb, nwx);
  gemm_kernel<<<nbx * nby, 256, 0, stream>>>(xb, BTb, out, N, nbx, nby);
}

// Round 16
// 54.529 us; speedup vs baseline: 1.6300x; 1.1137x over previous
//
#include <hip/hip_runtime.h>
#include <hip/hip_bf16.h>

typedef __attribute__((ext_vector_type(8))) short short8;
typedef __attribute__((ext_vector_type(4))) float floatx4;

#define L2EPS 1e-12f

__device__ __forceinline__ unsigned short f2bf(float f) {
  union { float f; unsigned u; } c; c.f = f;
  unsigned u = c.u;
  unsigned r = (u + 0x7fffu + ((u >> 16) & 1u)) >> 16;  // RNE
  return (unsigned short)r;
}

__device__ __forceinline__ void gload_lds16(const void* g, void* l) {
  __builtin_amdgcn_global_load_lds(
      (const __attribute__((address_space(1))) unsigned int*)g,
      (__attribute__((address_space(3))) unsigned int*)l,
      16, 0, 0);
}

// ---------------------------------------------------------------------------
// Kernel 1: per-row inverse L2 norm of W (D rows of length N). One block/row.
// ---------------------------------------------------------------------------
__global__ __launch_bounds__(256) void wnorm_kernel(const float* __restrict__ W,
                                                    float* __restrict__ rnw, int N) {
  const int d = blockIdx.x;
  const float2* row2 = (const float2*)(W + (size_t)d * N);
  const int n2 = N >> 1;
  float s = 0.f;
  for (int i = threadIdx.x; i < n2; i += 256) {
    const float2 v = row2[i];
    s += v.x * v.x + v.y * v.y;
  }
  if (threadIdx.x == 0 && (N & 1)) {
    const float v = W[(size_t)d * N + (N - 1)];
    s += v * v;
  }
#pragma unroll
  for (int off = 32; off > 0; off >>= 1) s += __shfl_xor(s, off);
  __shared__ float red[4];
  if ((threadIdx.x & 63) == 0) red[threadIdx.x >> 6] = s;
  __syncthreads();
  if (threadIdx.x == 0)
    rnw[d] = rsqrtf(fmaxf(red[0] + red[1] + red[2] + red[3], L2EPS));
}

// ---------------------------------------------------------------------------
// Kernel 2 (fused dispatch): blocks [0,nxb): normalize x rows AND fold rnw.
// Blocks [nxb,...): transpose-cast BT[n][d] = bf16(W[d][n]), zero-padded.
// ---------------------------------------------------------------------------
__global__ __launch_bounds__(256) void prep_kernel(const float* __restrict__ x,
                                                   const float* __restrict__ W,
                                                   const float* __restrict__ rnw,
                                                   unsigned short* __restrict__ xb,
                                                   unsigned short* __restrict__ BT,
                                                   int N, int nxb, int nwx) {
  const int bid = blockIdx.x;
  if (bid < nxb) {
    const int lane = threadIdx.x & 63;
    const int wave = threadIdx.x >> 6;
    const int row  = bid * 4 + wave;
    const float4* xr = (const float4*)(x + (size_t)row * 512);
    const float4 v0 = xr[lane * 2];
    const float4 v1 = xr[lane * 2 + 1];
    float s = v0.x*v0.x + v0.y*v0.y + v0.z*v0.z + v0.w*v0.w
            + v1.x*v1.x + v1.y*v1.y + v1.z*v1.z + v1.w*v1.w;
#pragma unroll
    for (int off = 32; off > 0; off >>= 1) s += __shfl_xor(s, off);
    const float r = rsqrtf(fmaxf(s, L2EPS));
    const float4 w0 = ((const float4*)rnw)[lane * 2];
    const float4 w1 = ((const float4*)rnw)[lane * 2 + 1];
    short8 o;
    o[0] = (short)f2bf(v0.x * r * w0.x); o[1] = (short)f2bf(v0.y * r * w0.y);
    o[2] = (short)f2bf(v0.z * r * w0.z); o[3] = (short)f2bf(v0.w * r * w0.w);
    o[4] = (short)f2bf(v1.x * r * w1.x); o[5] = (short)f2bf(v1.y * r * w1.y);
    o[6] = (short)f2bf(v1.z * r * w1.z); o[7] = (short)f2bf(v1.w * r * w1.w);
    *(short8*)(xb + (size_t)row * 512 + lane * 8) = o;
  } else {
    __shared__ unsigned short tile[32][33];
    const int wb = bid - nxb;
    const int n0 = (wb % nwx) * 32;
    const int d0 = (wb / nwx) * 32;
    const int tx = threadIdx.x & 31;
    const int ty = threadIdx.x >> 5;  // 0..7
#pragma unroll
    for (int i = 0; i < 4; ++i) {
      const int dl = ty + i * 8;
      const int n = n0 + tx;
      float v = 0.f;
      if (n < N) v = W[(size_t)(d0 + dl) * N + n];
      tile[tx][dl] = f2bf(v);
    }
    __syncthreads();
#pragma unroll
    for (int i = 0; i < 4; ++i) {
      const int nl = ty + i * 8;
      BT[(size_t)(n0 + nl) * 512 + d0 + tx] = tile[nl][tx];
    }
  }
}

// ---------------------------------------------------------------------------
// Kernel 3: EXACTLY-ONE-PASS GEMM. Tile 256x384, grid 16x16 = 256 blocks =
// 1 block/CU, one pass, zero tail: each CU pays ONE prologue + 8 drains +
// ONE epilogue for the entire GEMM. 8 waves (2M x 4N, wave = 128x96,
// acc 8x6 frags). BK=64, double-buffered LDS (2 x (A 32KB + B 48KB) =
// exactly 160KB). Per K-tile: stage next (10 instrs) -> compute current
// (96 MFMA/wave ~ 920 cyc/SIMD ~ HBM latency -> drain mostly covered) ->
// vmcnt(0) + one barrier. Chunk-XOR swizzle both sides (r3-measured 0
// conflicts); source pre-swizzled (rule #21). n-inner scalar epilogue
// (measured near-ideal WRITE ~103MB).
// ---------------------------------------------------------------------------
__global__ __launch_bounds__(512, 2) void gemm_kernel(
    const unsigned short* __restrict__ A,   // (4096,512) bf16 (xn * rnw)
    const unsigned short* __restrict__ BT,  // (6144,512) bf16 (W^T, padded)
    float* __restrict__ C,                  // (4096,N) f32
    int N) {
  __shared__ unsigned short As[2][256 * 64];   // 2 x 32 KB
  __shared__ unsigned short Bs[2][384 * 64];   // 2 x 48 KB

  const int tid = threadIdx.x;
  const int l   = tid & 63;
  const int w   = tid >> 6;   // 0..7
  const int wr  = w >> 2;     // 0..1  (M half)
  const int wc  = w & 3;      // 0..3  (N quarter)

  // XCD mapping: 256 blocks = 8 XCDs x 32; XCD c owns a 2bx x 16by strip
  // (B panels 2 x 384KB L2-resident; A via L3).
  const int bid = blockIdx.x;
  const int c   = bid & 7;
  const int i   = bid >> 3;                 // 0..31
  const int bx  = c * 2 + (i >> 4);         // 0..15
  const int by  = i & 15;                   // 0..15
  const int row0 = by * 256;
  const int col0 = bx * 384;

  floatx4 acc[8][6];
#pragma unroll
  for (int m = 0; m < 8; ++m)
#pragma unroll
    for (int n = 0; n < 6; ++n)
      acc[m][n] = (floatx4){0.f, 0.f, 0.f, 0.f};

  // staging: one instr = 512 thr x 16B = 8KB = 64 rows of 128B.
  // A: 4 instrs (256 rows), B: 6 instrs (384 rows). LDS dest linear
  // (tid*16B within instr); SOURCE chunk pre-swizzled:
  // chunk_g = (tid&7) ^ (srow&7); instr row-base is a multiple of 64 so
  // (row&7) == (srow&7) for all instrs.
  const int srow = tid >> 3;                               // 0..63
  const int sch  = ((tid & 7) ^ (srow & 7)) * 8;           // elems
  const unsigned short* Ap = A  + (size_t)(row0 + srow) * 512 + sch;
  const unsigned short* Bp = BT + (size_t)(col0 + srow) * 512 + sch;
  const int lo = tid * 8;                                  // LDS elems

#define STAGE(t_) do { \
    _Pragma("unroll") \
    for (int ii = 0; ii < 4; ++ii) \
      gload_lds16(Ap + (size_t)(ii * 64) * 512 + (t_) * 64, &As[(t_) & 1][ii * 4096 + lo]); \
    _Pragma("unroll") \
    for (int ii = 0; ii < 6; ++ii) \
      gload_lds16(Bp + (size_t)(ii * 64) * 512 + (t_) * 64, &Bs[(t_) & 1][ii * 4096 + lo]); \
  } while (0)

  // frag-read geometry: elem = row*64 + ((ks*4+q4)^(row&7))*8; consecutive
  // 8-lane groups cover 8 distinct 16B bank-groups (0 conflicts, r3-measured).
  const int ln15 = l & 15;
  const int q4   = l >> 4;
  const int e7   = ln15 & 7;
  const int cs0  = ((q4) ^ e7) * 8;
  const int cs1  = ((4 + q4) ^ e7) * 8;
  const int aoff = (wr * 128 + ln15) * 64;  // + m*1024
  const int boff = (wc * 96 + ln15) * 64;   // + n*1024

  // prologue: tile 0 staged, landed, published.
  STAGE(0);
  asm volatile("s_waitcnt vmcnt(0)" ::: "memory");
  __syncthreads();

#pragma unroll
  for (int t = 0; t < 8; ++t) {
    const int b = t & 1;
    if (t + 1 < 8) STAGE(t + 1);   // into other buffer; flies during compute
#pragma unroll
    for (int ks = 0; ks < 2; ++ks) {
      const int cs = ks ? cs1 : cs0;
      short8 af[8], bf[6];
#pragma unroll
      for (int m = 0; m < 8; ++m) af[m] = *(const short8*)&As[b][aoff + m * 1024 + cs];
#pragma unroll
      for (int n = 0; n < 6; ++n) bf[n] = *(const short8*)&Bs[b][boff + n * 1024 + cs];
#pragma unroll
      for (int m = 0; m < 8; ++m)
#pragma unroll
        for (int n = 0; n < 6; ++n)
          acc[m][n] = __builtin_amdgcn_mfma_f32_16x16x32_bf16(af[m], bf[n], acc[m][n], 0, 0, 0);
    }
    if (t + 1 < 8) {
      asm volatile("s_waitcnt vmcnt(0)" ::: "memory");  // tile t+1 landed
      __syncthreads();                                  // publish + reads of buf b done
    }
  }
#undef STAGE

  // epilogue: C/D layout col=lane&15, row=(lane>>4)*4+r; n-inner scalar.
  const int rb = row0 + wr * 128 + q4 * 4;
  const int cb = col0 + wc * 96 + ln15;
#pragma unroll
  for (int m = 0; m < 8; ++m) {
#pragma unroll
    for (int r = 0; r < 4; ++r) {
      const size_t o = (size_t)(rb + m * 16 + r) * N + cb;
#pragma unroll
      for (int n = 0; n < 6; ++n) {
        if (cb + n * 16 < N) C[o + n * 16] = acc[m][n][r];
      }
    }
  }
}

// ---------------------------------------------------------------------------
extern "C" void kernel_launch(void* const* d_in, const int* in_sizes, int n_in,
                              void* d_out, int out_size, void* d_ws, size_t ws_size,
                              hipStream_t stream) {
  const float* x = (const float*)d_in[0];
  const float* W = (const float*)d_in[1];
  float* out = (float*)d_out;

  const int D = 512;
  const int B = in_sizes[0] / D;            // 4096
  const int N = in_sizes[1] / D;            // 5994
  const int Npad = 6144;                    // 16 x 384

  char* ws = (char*)d_ws;
  unsigned short* xb  = (unsigned short*)ws;                          // B*D*2
  unsigned short* BTb = (unsigned short*)(ws + (size_t)B * D * 2);    // Npad*D*2
  float* rnw = (float*)(ws + (size_t)B * D * 2 + (size_t)Npad * D * 2);

  const int nxb = B / 4;           // 1024 xnorm blocks
  const int nwx = Npad / 32;       // 192 wtrans tiles per d-stripe
  const int nwb = nwx * (D / 32);  // 3072 wtrans blocks

  wnorm_kernel<<<D, 256, 0, stream>>>(W, rnw, N);
  prep_kernel<<<nxb + nwb, 256, 0, stream>>>(x, W, rnw, xb, BTb, N, nxb, nwx);
  gemm_kernel<<<(B / 256) * (Npad / 384), 512, 0, stream>>>(xb, BTb, out, N);
}